// Round 3
// baseline (204.927 us; speedup 1.0000x reference)
//
#include <hip/hip_runtime.h>
#include <cstdint>

#define B2 2
#define CCH 256
#define HH 64
#define WW 64
#define HWHW 4096
#define KOUT 324

// ---------------------------------------------------------------------------
// fmap2 (B,C,H,W) -> (B,HW,C) channel-last. grid (HW/32, C/32, B), block (32,8)
// ---------------------------------------------------------------------------
__global__ __launch_bounds__(256) void transpose_f2(
    const float* __restrict__ f2, float* __restrict__ f2t) {
  __shared__ float tile[32][33];
  int b = blockIdx.z;
  int hw0 = blockIdx.x * 32;
  int c0 = blockIdx.y * 32;
  int tx = threadIdx.x;
  int ty = threadIdx.y;
  const float* sb = f2 + (size_t)b * CCH * HWHW;
  float* db = f2t + (size_t)b * HWHW * CCH;
#pragma unroll
  for (int i = 0; i < 4; i++)
    tile[ty + i * 8][tx] = sb[(size_t)(c0 + ty + i * 8) * HWHW + hw0 + tx];
  __syncthreads();
#pragma unroll
  for (int i = 0; i < 4; i++)
    db[(size_t)(hw0 + ty + i * 8) * CCH + c0 + tx] = tile[tx][ty + i * 8];
}

// ---------------------------------------------------------------------------
// Pyramid levels 1..3 directly from level 0 (2^L x 2^L mean). Channel-last.
// ---------------------------------------------------------------------------
__global__ __launch_bounds__(256) void pool_all(
    const float4* __restrict__ l0, float4* __restrict__ l1,
    float4* __restrict__ l2, float4* __restrict__ l3) {
  int idx = blockIdx.x * blockDim.x + threadIdx.x;
  const int n1 = B2 * 32 * 32 * 64;
  const int n2 = B2 * 16 * 16 * 64;
  const int n3 = B2 * 8 * 8 * 64;
  int L, Wo, local;
  float4* dst;
  if (idx < n1) { L = 1; Wo = 32; local = idx; dst = l1; }
  else if (idx < n1 + n2) { L = 2; Wo = 16; local = idx - n1; dst = l2; }
  else if (idx < n1 + n2 + n3) { L = 3; Wo = 8; local = idx - n1 - n2; dst = l3; }
  else return;
  int f = 1 << L;
  int sh = 6 - L;
  int c4 = local & 63;
  int t = local >> 6;
  int x = t & (Wo - 1);
  int y = (t >> sh) & (Wo - 1);
  int b = t >> (2 * sh);
  const float4* src = l0 + ((size_t)b * HH * WW) * 64 + c4;
  float4 acc = make_float4(0.f, 0.f, 0.f, 0.f);
  for (int dy = 0; dy < f; dy++)
    for (int dx = 0; dx < f; dx++) {
      float4 a = src[(size_t)((y * f + dy) * WW + (x * f + dx)) * 64];
      acc.x += a.x; acc.y += a.y; acc.z += a.z; acc.w += a.w;
    }
  float s = 1.0f / (float)(f * f);
  acc.x *= s; acc.y *= s; acc.z *= s; acc.w *= s;
  dst[local] = acc;
}

// ---------------------------------------------------------------------------
// 16-lane sum via DPP (pure VALU, no LDS): quad xor1, quad xor2,
// row_half_mirror (i^7 within 8), row_mirror (i^15 within 16).
// All 16 lanes end with the group total.
// ---------------------------------------------------------------------------
__device__ __forceinline__ float dpp_sum16(float x) {
  int v;
  v = __builtin_amdgcn_update_dpp(0, __float_as_int(x), 0xB1, 0xF, 0xF, true);
  x += __int_as_float(v);
  v = __builtin_amdgcn_update_dpp(0, __float_as_int(x), 0x4E, 0xF, 0xF, true);
  x += __int_as_float(v);
  v = __builtin_amdgcn_update_dpp(0, __float_as_int(x), 0x141, 0xF, 0xF, true);
  x += __int_as_float(v);
  v = __builtin_amdgcn_update_dpp(0, __float_as_int(x), 0x140, 0xF, 0xF, true);
  x += __int_as_float(v);
  return x;
}

// ---------------------------------------------------------------------------
// Main: one block per query, wave = pyramid level, XCD-contiguous swizzle.
// 4 taps in flight per wave (16 lanes/tap, 16 ch/lane). Branchless OOB via
// clamped address + cndmask. fmap1 fragment read directly from (B,C,H,W)
// (one scalar load per thread), pre-scaled by 1/sqrt(C)=1/16.
// ---------------------------------------------------------------------------
__global__ __launch_bounds__(256) void sample_k(
    const float* __restrict__ fmap1,
    const float* __restrict__ coords,
    const float* __restrict__ f2l0, const float* __restrict__ f2l1,
    const float* __restrict__ f2l2, const float* __restrict__ f2l3,
    float* __restrict__ pout) {
  __shared__ float f1sc[CCH];
  __shared__ float P[4][100];
  int bid = blockIdx.x;
  int n = ((bid & 7) << 10) | (bid >> 3);  // XCD-contiguous chunks
  int b = n >> 12;
  int i = n & 4095;
  int yi = i >> 6, xi = i & 63;
  int tid = threadIdx.x;
  f1sc[tid] = fmap1[((size_t)b * CCH + tid) * HWHW + i] * 0.0625f;
  float clx = coords[(size_t)(b * 2 + 0) * HWHW + i];
  float cly = coords[(size_t)(b * 2 + 1) * HWHW + i];
  __syncthreads();

  int l = tid >> 6;    // wave index = level
  int lane = tid & 63;
  int lg = lane >> 4;  // which of 4 concurrent taps
  int l16 = lane & 15; // channel-group lane within tap

  float inv = 1.0f / (float)(1 << l);
  float xl = clx * inv, yl = cly * inv;
  float fx = floorf(xl), fy = floorf(yl);
  int ix0 = (int)fx - 4, iy0 = (int)fy - 4;
  float wx1 = xl - fx, wx0 = 1.0f - wx1;
  float wy1 = yl - fy, wy0 = 1.0f - wy1;
  int Hl = HH >> l, Wl = WW >> l;
  const float* f2 = (l == 0) ? f2l0 : (l == 1) ? f2l1 : (l == 2) ? f2l2 : f2l3;
  const float4* f2b = (const float4*)(f2) + (size_t)b * Hl * Wl * 64 + l16;

  const float4* f1v = (const float4*)f1sc;
  float4 f1c0 = f1v[l16];
  float4 f1c1 = f1v[16 + l16];
  float4 f1c2 = f1v[32 + l16];
  float4 f1c3 = f1v[48 + l16];

  // taps t = it*4 + lg; u = t/10 (x index), v = t%10 (y index), incremental
  int u = 0, v = lg, t = lg;
#pragma unroll 5
  for (int it = 0; it < 25; it++) {
    int txp = ix0 + u, typ = iy0 + v;
    bool inb = ((unsigned)txp < (unsigned)Wl) & ((unsigned)typ < (unsigned)Hl);
    int txc = min(max(txp, 0), Wl - 1);
    int tyc = min(max(typ, 0), Hl - 1);
    const float4* tp = f2b + (size_t)(tyc * Wl + txc) * 64;
    float4 a0 = tp[0];
    float4 a1 = tp[16];
    float4 a2 = tp[32];
    float4 a3 = tp[48];
    float d = a0.x * f1c0.x + a0.y * f1c0.y + a0.z * f1c0.z + a0.w * f1c0.w
            + a1.x * f1c1.x + a1.y * f1c1.y + a1.z * f1c1.z + a1.w * f1c1.w
            + a2.x * f1c2.x + a2.y * f1c2.y + a2.z * f1c2.z + a2.w * f1c2.w
            + a3.x * f1c3.x + a3.y * f1c3.y + a3.z * f1c3.z + a3.w * f1c3.w;
    d = inb ? d : 0.0f;
    d = dpp_sum16(d);
    if (l16 == 0) P[l][t] = d;
    t += 4;
    v += 4;
    bool wrap = v >= 10;
    v = wrap ? v - 10 : v;
    u = wrap ? u + 1 : u;
  }
  __syncthreads();

  float* po = pout + (size_t)n * KOUT + l * 81;
  {
    int k = lane;  // 0..63
    int a = k / 9, bb = k - a * 9;
    float val = wy0 * (wx0 * P[l][a * 10 + bb] + wx1 * P[l][(a + 1) * 10 + bb])
              + wy1 * (wx0 * P[l][a * 10 + bb + 1] + wx1 * P[l][(a + 1) * 10 + bb + 1]);
    po[k] = val;
  }
  if (lane < 17) {
    int k = lane + 64;
    int a = k / 9, bb = k - a * 9;
    float val = wy0 * (wx0 * P[l][a * 10 + bb] + wx1 * P[l][(a + 1) * 10 + bb])
              + wy1 * (wx0 * P[l][a * 10 + bb + 1] + wx1 * P[l][(a + 1) * 10 + bb + 1]);
    po[k] = val;
  }
}

// ---------------------------------------------------------------------------
// (B, HW, 324) -> (B, 324, HW) tiled transpose, coalesced both sides.
// ---------------------------------------------------------------------------
__global__ __launch_bounds__(256) void writeout(
    const float* __restrict__ pout, float* __restrict__ out) {
  __shared__ float tile[32][33];
  int b = blockIdx.z;
  int hw0 = blockIdx.x * 32;
  int ch0 = blockIdx.y * 32;
  int tx = threadIdx.x, ty = threadIdx.y;
  const float* pb = pout + (size_t)b * HWHW * KOUT;
  float* ob = out + (size_t)b * KOUT * HWHW;
  if (ch0 + tx < KOUT) {
#pragma unroll
    for (int i = 0; i < 4; i++)
      tile[ty + i * 8][tx] = pb[(size_t)(hw0 + ty + i * 8) * KOUT + ch0 + tx];
  }
  __syncthreads();
#pragma unroll
  for (int i = 0; i < 4; i++) {
    int ch = ch0 + ty + i * 8;
    if (ch < KOUT)
      ob[(size_t)ch * HWHW + hw0 + tx] = tile[tx][ty + i * 8];
  }
}

// ---------------------------------------------------------------------------
extern "C" void kernel_launch(void* const* d_in, const int* in_sizes, int n_in,
                              void* d_out, int out_size, void* d_ws, size_t ws_size,
                              hipStream_t stream) {
  const float* fmap1 = (const float*)d_in[0];
  const float* fmap2 = (const float*)d_in[1];
  const float* coords = (const float*)d_in[2];
  float* out = (float*)d_out;

  char* ws = (char*)d_ws;
  float* f2l0 = (float*)(ws);                          // 8 MB   (B,64,64,C)
  float* f2l1 = (float*)(ws + ((size_t)8 << 20));      // 2 MB   (B,32,32,C)
  float* f2l2 = (float*)(ws + ((size_t)10 << 20));     // 512 KB (B,16,16,C)
  float* f2l3 = (float*)(ws + ((size_t)10 << 20) + ((size_t)512 << 10)); // 128 KB
  float* pout = (float*)(ws + ((size_t)11 << 20));     // 10.6MB (B*HW, 324)

  dim3 tb(32, 8, 1);
  dim3 tg(HWHW / 32, CCH / 32, B2);
  transpose_f2<<<tg, tb, 0, stream>>>(fmap2, f2l0);

  int npool = B2 * (32 * 32 + 16 * 16 + 8 * 8) * 64;
  pool_all<<<(npool + 255) / 256, 256, 0, stream>>>(
      (const float4*)f2l0, (float4*)f2l1, (float4*)f2l2, (float4*)f2l3);

  sample_k<<<HWHW * B2, 256, 0, stream>>>(fmap1, coords, f2l0, f2l1, f2l2, f2l3, pout);

  dim3 wb(32, 8, 1);
  dim3 wg(HWHW / 32, (KOUT + 31) / 32, B2);
  writeout<<<wg, wb, 0, stream>>>(pout, out);
}

// Round 4
// 147.733 us; speedup vs baseline: 1.3871x; 1.3871x over previous
//
#include <hip/hip_runtime.h>
#include <cstdint>

#define B2 2
#define CCH 256
#define HH 64
#define WW 64
#define HWHW 4096
#define KOUT 324

typedef _Float16 half_t;
typedef _Float16 h2 __attribute__((ext_vector_type(2)));

#if !__has_builtin(__builtin_amdgcn_fdot2)
#define NO_FDOT2 1
#endif

__device__ __forceinline__ float fdot2f(h2 a, h2 b, float c) {
#ifdef NO_FDOT2
  return c + (float)a.x * (float)b.x + (float)a.y * (float)b.y;
#else
  return __builtin_amdgcn_fdot2(a, b, c, false);
#endif
}

// ---------------------------------------------------------------------------
// (B,C,H,W) fp32 -> (B,HW,C) f16 channel-last. z<2: fmap1 (scaled 1/16),
// z>=2: fmap2. grid (HW/32, C/32, 4), block (32,8).
// ---------------------------------------------------------------------------
__global__ __launch_bounds__(256) void transpose_cl(
    const float* __restrict__ f1, const float* __restrict__ f2,
    half_t* __restrict__ f1t, half_t* __restrict__ f2t) {
  __shared__ float tile[32][33];
  int zz = blockIdx.z;
  const float* src = (zz < 2) ? f1 : f2;
  half_t* dst = (zz < 2) ? f1t : f2t;
  float s = (zz < 2) ? 0.0625f : 1.0f;   // fold 1/sqrt(256) into fmap1
  int b = zz & 1;
  int hw0 = blockIdx.x * 32;
  int c0 = blockIdx.y * 32;
  int tx = threadIdx.x;
  int ty = threadIdx.y;
  const float* sb = src + (size_t)b * CCH * HWHW;
  half_t* db = dst + (size_t)b * HWHW * CCH;
#pragma unroll
  for (int i = 0; i < 4; i++)
    tile[ty + i * 8][tx] = sb[(size_t)(c0 + ty + i * 8) * HWHW + hw0 + tx];
  __syncthreads();
#pragma unroll
  for (int i = 0; i < 4; i++)
    db[(size_t)(hw0 + ty + i * 8) * CCH + c0 + tx] = (half_t)(tile[tx][ty + i * 8] * s);
}

// ---------------------------------------------------------------------------
// Pyramid levels 1..3 from level 0 (2^L x 2^L mean), f16 in/out, fp32 accum.
// Thread owns one half2 (2 channels) of one output pixel.
// ---------------------------------------------------------------------------
__global__ __launch_bounds__(256) void pool_all(
    const h2* __restrict__ l0, h2* __restrict__ l1,
    h2* __restrict__ l2, h2* __restrict__ l3) {
  int idx = blockIdx.x * blockDim.x + threadIdx.x;
  const int n1 = B2 * 32 * 32 * 128;
  const int n2 = B2 * 16 * 16 * 128;
  const int n3 = B2 * 8 * 8 * 128;
  int L, Wo, local;
  h2* dst;
  if (idx < n1) { L = 1; Wo = 32; local = idx; dst = l1; }
  else if (idx < n1 + n2) { L = 2; Wo = 16; local = idx - n1; dst = l2; }
  else if (idx < n1 + n2 + n3) { L = 3; Wo = 8; local = idx - n1 - n2; dst = l3; }
  else return;
  int f = 1 << L;
  int sh = 6 - L;
  int c2 = local & 127;
  int t = local >> 7;
  int x = t & (Wo - 1);
  int y = (t >> sh) & (Wo - 1);
  int b = t >> (2 * sh);
  const h2* src = l0 + (size_t)b * HWHW * 128 + c2;
  float ax = 0.f, ay = 0.f;
  for (int dy = 0; dy < f; dy++)
    for (int dx = 0; dx < f; dx++) {
      h2 a = src[(size_t)((y * f + dy) * WW + (x * f + dx)) * 128];
      ax += (float)a.x; ay += (float)a.y;
    }
  float s = 1.0f / (float)(f * f);
  h2 r;
  r.x = (half_t)(ax * s);
  r.y = (half_t)(ay * s);
  dst[local] = r;
}

// ---------------------------------------------------------------------------
// 16-lane sum via DPP (pure VALU): quad xor1, quad xor2, row_half_mirror,
// row_mirror. All 16 lanes end with the group total.
// ---------------------------------------------------------------------------
__device__ __forceinline__ float dpp_sum16(float x) {
  int v;
  v = __builtin_amdgcn_update_dpp(0, __float_as_int(x), 0xB1, 0xF, 0xF, true);
  x += __int_as_float(v);
  v = __builtin_amdgcn_update_dpp(0, __float_as_int(x), 0x4E, 0xF, 0xF, true);
  x += __int_as_float(v);
  v = __builtin_amdgcn_update_dpp(0, __float_as_int(x), 0x141, 0xF, 0xF, true);
  x += __int_as_float(v);
  v = __builtin_amdgcn_update_dpp(0, __float_as_int(x), 0x140, 0xF, 0xF, true);
  x += __int_as_float(v);
  return x;
}

// ---------------------------------------------------------------------------
// Main: one block per query, wave = level, XCD-contiguous swizzle.
// 4 taps in flight per wave; 16 lanes per tap; lane owns 8ch of the low half
// (via load A) and 8ch of the high half (via load B) -> two fully-contiguous
// 256B load instructions per tap. Dots via v_dot2_f32_f16 (fp32 accum).
// OOB taps exec-masked off (no loads, d=0).
// ---------------------------------------------------------------------------
__global__ __launch_bounds__(256) void sample_k(
    const float* __restrict__ coords,
    const half_t* __restrict__ f1t,
    const half_t* __restrict__ f2l0, const half_t* __restrict__ f2l1,
    const half_t* __restrict__ f2l2, const half_t* __restrict__ f2l3,
    float* __restrict__ pout) {
  __shared__ float4 f1s4[32];   // 512B: one query's 256 f16 channels
  __shared__ float P[4][100];
  int bid = blockIdx.x;
  int n = ((bid & 7) << 10) | (bid >> 3);  // XCD-contiguous chunks
  int b = n >> 12;
  int i = n & 4095;
  int tid = threadIdx.x;
  if (tid < 32) f1s4[tid] = ((const float4*)(f1t + (size_t)n * CCH))[tid];
  float clx = coords[(size_t)(b * 2 + 0) * HWHW + i];
  float cly = coords[(size_t)(b * 2 + 1) * HWHW + i];
  __syncthreads();

  int l = tid >> 6;    // wave index = level
  int lane = tid & 63;
  int lg = lane >> 4;  // which of 4 concurrent taps
  int l16 = lane & 15; // channel-group lane within tap

  float inv = 1.0f / (float)(1 << l);
  float xl = clx * inv, yl = cly * inv;
  float fx = floorf(xl), fy = floorf(yl);
  int ix0 = (int)fx - 4, iy0 = (int)fy - 4;
  float wx1 = xl - fx, wx0 = 1.0f - wx1;
  float wy1 = yl - fy, wy0 = 1.0f - wy1;
  int Hl = HH >> l, Wl = WW >> l;
  const half_t* f2 = (l == 0) ? f2l0 : (l == 1) ? f2l1 : (l == 2) ? f2l2 : f2l3;
  // 32 float4 (512B) per pixel; +l16 -> lane's 16B slice of the low 256B
  const float4* f2b = (const float4*)(f2) + (size_t)b * Hl * Wl * 32 + l16;

  // f1 fragments: lane owns ch [l16*8, l16*8+8) and [128+l16*8, 128+l16*8+8)
  const h2* f1h = (const h2*)f1s4;
  h2 fa0 = f1h[l16 * 4 + 0], fa1 = f1h[l16 * 4 + 1];
  h2 fa2 = f1h[l16 * 4 + 2], fa3 = f1h[l16 * 4 + 3];
  h2 fb0 = f1h[64 + l16 * 4 + 0], fb1 = f1h[64 + l16 * 4 + 1];
  h2 fb2 = f1h[64 + l16 * 4 + 2], fb3 = f1h[64 + l16 * 4 + 3];

  // taps t = it*4 + lg; u = t/10 (x index), v = t%10 (y index), incremental
  int u = 0, v = lg, t = lg;
  for (int it = 0; it < 25; it++) {
    int txp = ix0 + u, typ = iy0 + v;
    bool inb = ((unsigned)txp < (unsigned)Wl) & ((unsigned)typ < (unsigned)Hl);
    float d = 0.0f;
    if (inb) {
      const float4* tp = f2b + (size_t)(typ * Wl + txp) * 32;
      float4 A = tp[0];    // ch l16*8   .. +7 (low half of channels)
      float4 Bv = tp[16];  // ch 128+l16*8 .. +7 (high half)
      const h2* ah = (const h2*)&A;
      const h2* bh = (const h2*)&Bv;
      d = fdot2f(ah[0], fa0, d);
      d = fdot2f(ah[1], fa1, d);
      d = fdot2f(ah[2], fa2, d);
      d = fdot2f(ah[3], fa3, d);
      d = fdot2f(bh[0], fb0, d);
      d = fdot2f(bh[1], fb1, d);
      d = fdot2f(bh[2], fb2, d);
      d = fdot2f(bh[3], fb3, d);
    }
    d = dpp_sum16(d);
    if (l16 == 0) P[l][t] = d;   // f1 pre-scaled by 1/16
    t += 4;
    v += 4;
    bool wrap = v >= 10;
    v = wrap ? v - 10 : v;
    u = wrap ? u + 1 : u;
  }
  __syncthreads();

  float* po = pout + (size_t)n * KOUT + l * 81;
  {
    int k = lane;  // 0..63
    int a = k / 9, bb = k - a * 9;
    float val = wy0 * (wx0 * P[l][a * 10 + bb] + wx1 * P[l][(a + 1) * 10 + bb])
              + wy1 * (wx0 * P[l][a * 10 + bb + 1] + wx1 * P[l][(a + 1) * 10 + bb + 1]);
    po[k] = val;
  }
  if (lane < 17) {
    int k = lane + 64;
    int a = k / 9, bb = k - a * 9;
    float val = wy0 * (wx0 * P[l][a * 10 + bb] + wx1 * P[l][(a + 1) * 10 + bb])
              + wy1 * (wx0 * P[l][a * 10 + bb + 1] + wx1 * P[l][(a + 1) * 10 + bb + 1]);
    po[k] = val;
  }
}

// ---------------------------------------------------------------------------
// (B, HW, 324) -> (B, 324, HW) tiled transpose, coalesced both sides.
// ---------------------------------------------------------------------------
__global__ __launch_bounds__(256) void writeout(
    const float* __restrict__ pout, float* __restrict__ out) {
  __shared__ float tile[32][33];
  int b = blockIdx.z;
  int hw0 = blockIdx.x * 32;
  int ch0 = blockIdx.y * 32;
  int tx = threadIdx.x, ty = threadIdx.y;
  const float* pb = pout + (size_t)b * HWHW * KOUT;
  float* ob = out + (size_t)b * KOUT * HWHW;
  if (ch0 + tx < KOUT) {
#pragma unroll
    for (int i = 0; i < 4; i++)
      tile[ty + i * 8][tx] = pb[(size_t)(hw0 + ty + i * 8) * KOUT + ch0 + tx];
  }
  __syncthreads();
#pragma unroll
  for (int i = 0; i < 4; i++) {
    int ch = ch0 + ty + i * 8;
    if (ch < KOUT)
      ob[(size_t)ch * HWHW + hw0 + tx] = tile[tx][ty + i * 8];
  }
}

// ---------------------------------------------------------------------------
extern "C" void kernel_launch(void* const* d_in, const int* in_sizes, int n_in,
                              void* d_out, int out_size, void* d_ws, size_t ws_size,
                              hipStream_t stream) {
  const float* fmap1 = (const float*)d_in[0];
  const float* fmap2 = (const float*)d_in[1];
  const float* coords = (const float*)d_in[2];
  float* out = (float*)d_out;

  char* ws = (char*)d_ws;
  half_t* f1t  = (half_t*)(ws);                        // 4 MB   (B,HW,C) f16, pre-scaled
  half_t* f2l0 = (half_t*)(ws + ((size_t)4 << 20));    // 4 MB   (B,64,64,C) f16
  half_t* f2l1 = (half_t*)(ws + ((size_t)8 << 20));    // 1 MB   (B,32,32,C) f16
  half_t* f2l2 = (half_t*)(ws + ((size_t)9 << 20));    // 256 KB (B,16,16,C) f16
  half_t* f2l3 = (half_t*)(ws + ((size_t)9 << 20) + ((size_t)512 << 10)); // 64 KB
  float*  pout = (float*)(ws + ((size_t)10 << 20));    // 10.6MB (B*HW, 324) fp32

  dim3 tb(32, 8, 1);
  dim3 tg(HWHW / 32, CCH / 32, 4);
  transpose_cl<<<tg, tb, 0, stream>>>(fmap1, fmap2, f1t, f2l0);

  int npool = B2 * (32 * 32 + 16 * 16 + 8 * 8) * 128;
  pool_all<<<(npool + 255) / 256, 256, 0, stream>>>(
      (const h2*)f2l0, (h2*)f2l1, (h2*)f2l2, (h2*)f2l3);

  sample_k<<<HWHW * B2, 256, 0, stream>>>(coords, f1t, f2l0, f2l1, f2l2, f2l3, pout);

  dim3 wb(32, 8, 1);
  dim3 wg(HWHW / 32, (KOUT + 31) / 32, B2);
  writeout<<<wg, wb, 0, stream>>>(pout, out);
}